// Round 2
// baseline (200.152 us; speedup 1.0000x reference)
//
#include <hip/hip_runtime.h>
#include <math.h>

#define BATCH 2
#define NNODE 512
#define DIN   128
#define DOUT  128
#define DE    32
#define NEG   0.2f

// ---------------------------------------------------------------------------
// Kernel 1: x_l = x@W_l + b_l ; x_r = x@W_r + b_r     (tiny: 34M FMA total)
// ---------------------------------------------------------------------------
__global__ __launch_bounds__(128) void xlr_kernel(
    const float* __restrict__ x,  const float* __restrict__ Wl,
    const float* __restrict__ bl, const float* __restrict__ Wr,
    const float* __restrict__ br, float* __restrict__ xl,
    float* __restrict__ xr)
{
    const int row = blockIdx.x;        // b*N + i
    const int d   = threadIdx.x;       // 0..127
    __shared__ float xs[DIN];
    xs[d] = x[row * DIN + d];
    __syncthreads();
    float al = bl[d], ar = br[d];
    #pragma unroll 8
    for (int k = 0; k < DIN; ++k) {
        const float xv = xs[k];
        al = fmaf(xv, Wl[k * DOUT + d], al);
        ar = fmaf(xv, Wr[k * DOUT + d], ar);
    }
    xl[row * DOUT + d] = al;
    xr[row * DOUT + d] = ar;
}

// ---------------------------------------------------------------------------
// Kernel 2: per (b,i): scores over all j, softmax, aggregate, bias, mask, silu
// adj/mask dtype detected at runtime from adj's raw words:
//   word == 0x3f800000 possible only for float32 bools (bytes 0,0,128,63)
//   word > 1 (and no float-one) only for byte-packed bools (bytes in {0,1})
//   all words in {0,1} -> int32 bools
// ---------------------------------------------------------------------------
__global__ __launch_bounds__(256) void gat_main(
    const float* __restrict__ xl, const float* __restrict__ xr,
    const void* __restrict__ adjv, const float* __restrict__ e,
    const void* __restrict__ maskv, const float* __restrict__ We,
    const float* __restrict__ att, const float* __restrict__ bias,
    float* __restrict__ out)
{
    const int bi   = blockIdx.x;          // b*N + i
    const int b    = bi >> 9;             // / 512
    const int i    = bi & (NNODE - 1);
    const int t    = threadIdx.x;
    const int wave = t >> 6;
    const int lane = t & 63;

    __shared__ float We_s[DE * DOUT];     // 16 KB
    __shared__ float att_s[DOUT];
    __shared__ float xr_s[DOUT];
    __shared__ float sc_s[NNODE];         // scores -> exp weights
    __shared__ float es[32 * DE];         // 4 KB e-tile (32 j's)
    __shared__ float red_s[8];
    __shared__ float op_s[2][DOUT];
    __shared__ int   mflag[2];            // [0]=saw float-one, [1]=saw >1

    if (t < 2) mflag[t] = 0;
    for (int idx = t; idx < DE * DOUT; idx += 256) We_s[idx] = We[idx];
    if (t < DOUT) { att_s[t] = att[t]; xr_s[t] = xr[bi * DOUT + t]; }
    __syncthreads();

    // ---- dtype probe: scan first 4096 words of adj (L2-resident) ----
    {
        const unsigned* aw = (const unsigned*)adjv;
        unsigned sawF = 0, sawG = 0;
        #pragma unroll
        for (int k = 0; k < 16; ++k) {
            const unsigned w = aw[t + 256 * k];
            sawF |= (w == 0x3f800000u);
            sawG |= (w > 1u);
        }
        if (sawF) atomicOr(&mflag[0], 1);
        if (sawG) atomicOr(&mflag[1], 1);
    }
    __syncthreads();
    // mode: 1 = byte-bools; 0 = 4-byte elements (int32 or float32: nonzero-bits test)
    const int byteMode = (!mflag[0] && mflag[1]) ? 1 : 0;

    const float* xlb = xl + (size_t)b * NNODE * DOUT;
    const float* eb  = e  + (size_t)bi * NNODE * DE;
    const unsigned char* adjB = (const unsigned char*)adjv + (size_t)bi * NNODE;
    const unsigned*      adjW = (const unsigned*)adjv + (size_t)bi * NNODE;

    const int   d0  = lane, d1 = lane + 64;
    const float xr0 = xr_s[d0], xr1 = xr_s[d1];
    const float a0  = att_s[d0], a1 = att_s[d1];

    for (int jt = 0; jt < NNODE; jt += 32) {
        // stage e[b,i,jt:jt+32,:] (1024 floats) -> LDS, coalesced float4
        {
            const float4* src = (const float4*)(eb + (size_t)jt * DE);
            float4*       dst = (float4*)es;
            dst[t] = src[t];
        }
        __syncthreads();

        for (int s = 0; s < 8; ++s) {
            const int jo = wave + 4 * s;
            const int j  = jt + jo;
            const float* ejs = es + jo * DE;       // wave-uniform -> LDS broadcast
            float et0 = 0.f, et1 = 0.f;
            #pragma unroll
            for (int k = 0; k < DE; ++k) {
                const float ev = ejs[k];
                et0 = fmaf(ev, We_s[k * DOUT + d0], et0);  // stride-1: 2 lanes/bank, free
                et1 = fmaf(ev, We_s[k * DOUT + d1], et1);
            }
            float p0 = et0 + xr0 + xlb[(size_t)j * DOUT + d0];
            float p1 = et1 + xr1 + xlb[(size_t)j * DOUT + d1];
            p0 = p0 > 0.f ? p0 : NEG * p0;
            p1 = p1 > 0.f ? p1 : NEG * p1;
            float c = fmaf(a0, p0, a1 * p1);
            #pragma unroll
            for (int off = 32; off; off >>= 1) c += __shfl_xor(c, off, 64);
            if (lane == 0) {
                const bool conn = (j == i) ||
                    (byteMode ? (adjB[j] != 0) : (adjW[j] != 0));  // adj | eye
                sc_s[j] = conn ? c : -1e30f;
            }
        }
        __syncthreads();
    }

    // ---- softmax over 512 scores ----
    float m = fmaxf(sc_s[t], sc_s[t + 256]);
    #pragma unroll
    for (int off = 32; off; off >>= 1) m = fmaxf(m, __shfl_xor(m, off, 64));
    if (lane == 0) red_s[wave] = m;
    __syncthreads();
    m = fmaxf(fmaxf(red_s[0], red_s[1]), fmaxf(red_s[2], red_s[3]));

    const float e0 = __expf(sc_s[t] - m);
    const float e1 = __expf(sc_s[t + 256] - m);
    sc_s[t] = e0; sc_s[t + 256] = e1;   // each thread touches only its own 2 slots
    float ssum = e0 + e1;
    #pragma unroll
    for (int off = 32; off; off >>= 1) ssum += __shfl_xor(ssum, off, 64);
    if (lane == 0) red_s[4 + wave] = ssum;
    __syncthreads();
    const float inv = 1.f / (red_s[4] + red_s[5] + red_s[6] + red_s[7]);

    // ---- out[b,i,d] = (sum_j w_j * x_l[b,j,d]) * inv + bias[d], mask, silu ----
    const int d = t & (DOUT - 1), half = t >> 7;
    float acc = 0.f;
    const float* xlh  = xlb + (size_t)half * 256 * DOUT;
    const float* wrow = sc_s + half * 256;
    for (int j = 0; j < 256; ++j)
        acc = fmaf(wrow[j], xlh[(size_t)j * DOUT + d], acc);
    op_s[half][d] = acc;
    __syncthreads();

    if (t < DOUT) {
        const bool mv = byteMode ? (((const unsigned char*)maskv)[bi] != 0)
                                 : (((const unsigned*)maskv)[bi] != 0);
        float v = (op_s[0][t] + op_s[1][t]) * inv + bias[t];
        if (!mv) v = 0.f;
        v = v / (1.f + __expf(-v));          // silu
        out[(size_t)bi * DOUT + t] = v;
    }
}

// ---------------------------------------------------------------------------
extern "C" void kernel_launch(void* const* d_in, const int* in_sizes, int n_in,
                              void* d_out, int out_size, void* d_ws, size_t ws_size,
                              hipStream_t stream)
{
    const float* x    = (const float*)d_in[0];
    const void*  adj  = d_in[1];                 // bool: dtype detected on device
    const float* e    = (const float*)d_in[2];
    const void*  mask = d_in[3];                 // bool: dtype detected on device
    const float* Wl   = (const float*)d_in[4];
    const float* bl   = (const float*)d_in[5];
    const float* Wr   = (const float*)d_in[6];
    const float* br   = (const float*)d_in[7];
    const float* We   = (const float*)d_in[8];
    const float* att  = (const float*)d_in[9];
    const float* bias = (const float*)d_in[10];
    float*       out  = (float*)d_out;

    float* xl = (float*)d_ws;                              // [B*N, 128]
    float* xr = xl + (size_t)BATCH * NNODE * DOUT;         // [B*N, 128]

    xlr_kernel<<<BATCH * NNODE, 128, 0, stream>>>(x, Wl, bl, Wr, br, xl, xr);
    gat_main<<<BATCH * NNODE, 256, 0, stream>>>(xl, xr, adj, e, mask, We,
                                                att, bias, out);
}

// Round 4
// 54.661 us; speedup vs baseline: 3.6617x; 3.6617x over previous
//
#include <hip/hip_runtime.h>
#include <math.h>

#define BATCH 2
#define NNODE 512
#define DIN   128
#define DOUT  128
#define DE    32
#define NEG   0.2f

typedef __attribute__((ext_vector_type(8))) short bf16x8;
typedef __attribute__((ext_vector_type(4))) float f32x4;

__device__ inline short f2bf(float f) {   // RNE f32 -> bf16
    union { float f; unsigned u; } v; v.f = f;
    unsigned r = v.u + 0x7fffu + ((v.u >> 16) & 1u);
    return (short)(r >> 16);
}

// ---------------------------------------------------------------------------
// Kernel 1: x_l = x@W_l + b_l ; x_r = x@W_r + b_r
// 4 rows per block (256 blocks x 256 thr) so weight reads amortize 4x.
// ---------------------------------------------------------------------------
__global__ __launch_bounds__(256) void xlr_kernel(
    const float* __restrict__ x,  const float* __restrict__ Wl,
    const float* __restrict__ bl, const float* __restrict__ Wr,
    const float* __restrict__ br, float* __restrict__ xl,
    float* __restrict__ xr)
{
    const int r0 = blockIdx.x * 4;         // first of 4 rows
    const int d  = threadIdx.x & 127;
    const int hv = threadIdx.x >> 7;       // 0/1 -> rows r0+2*hv, r0+2*hv+1
    __shared__ float xs[4][DIN];
    for (int idx = threadIdx.x; idx < 4 * DIN; idx += 256)
        xs[idx >> 7][idx & 127] = x[(size_t)r0 * DIN + idx];
    __syncthreads();
    const int ra = 2 * hv, rb = ra + 1;
    float al0 = bl[d], al1 = al0, ar0 = br[d], ar1 = ar0;
    #pragma unroll 4
    for (int k = 0; k < DIN; ++k) {
        const float wl = Wl[k * DOUT + d], wr = Wr[k * DOUT + d];
        const float xa = xs[ra][k], xb = xs[rb][k];
        al0 = fmaf(xa, wl, al0); al1 = fmaf(xb, wl, al1);
        ar0 = fmaf(xa, wr, ar0); ar1 = fmaf(xb, wr, ar1);
    }
    xl[(size_t)(r0 + ra) * DOUT + d] = al0;
    xl[(size_t)(r0 + rb) * DOUT + d] = al1;
    xr[(size_t)(r0 + ra) * DOUT + d] = ar0;
    xr[(size_t)(r0 + rb) * DOUT + d] = ar1;
}

// ---------------------------------------------------------------------------
// Kernel 2: per (b,i). Score phase on MFMA (e@We bf16), epilogue VALU,
// softmax, VALU aggregation. No barriers inside the score loop.
// ---------------------------------------------------------------------------
__global__ __launch_bounds__(256, 4) void gat_main(
    const float* __restrict__ xl, const float* __restrict__ xr,
    const void* __restrict__ adjv, const float* __restrict__ e,
    const void* __restrict__ maskv, const float* __restrict__ We,
    const float* __restrict__ att, const float* __restrict__ bias,
    float* __restrict__ out)
{
    const int bi   = blockIdx.x;          // b*N + i
    const int b    = bi >> 9;
    const int i    = bi & (NNODE - 1);
    const int t    = threadIdx.x;
    const int wave = t >> 6;
    const int lane = t & 63;
    const int col  = lane & 15;           // MFMA col / A-row index
    const int g    = lane >> 4;           // k-chunk / C-row group

    __shared__ short WeT_s[DOUT][DE];     // [d][k] bf16, 8 KB
    __shared__ float att_s[DOUT];
    __shared__ float xr_s[DOUT];
    __shared__ float sc_s[NNODE];
    __shared__ float red_s[8];
    __shared__ float op_s[2][DOUT];
    __shared__ int   mflag[2];

    if (t < 2) mflag[t] = 0;
    for (int idx = t; idx < DE * DOUT; idx += 256) {
        const int k = idx >> 7, d = idx & 127;
        WeT_s[d][k] = f2bf(We[idx]);
    }
    if (t < DOUT) { att_s[t] = att[t]; xr_s[t] = xr[(size_t)bi * DOUT + t]; }
    __syncthreads();

    // ---- adj/mask dtype probe (first 16 KB of adj, L2-resident) ----
    {
        const unsigned* aw = (const unsigned*)adjv;
        unsigned sawF = 0, sawG = 0;
        #pragma unroll
        for (int k = 0; k < 16; ++k) {
            const unsigned w = aw[t + 256 * k];
            sawF |= (w == 0x3f800000u);
            sawG |= (w > 1u);
        }
        if (sawF) atomicOr(&mflag[0], 1);
        if (sawG) atomicOr(&mflag[1], 1);
    }
    __syncthreads();
    const int byteMode = (!mflag[0] && mflag[1]) ? 1 : 0;

    const float* xlb = xl + (size_t)b * NNODE * DOUT;
    const float* eb  = e  + (size_t)bi * NNODE * DE;
    const unsigned char* adjB = (const unsigned char*)adjv + (size_t)bi * NNODE;
    const unsigned*      adjW = (const unsigned*)adjv + (size_t)bi * NNODE;

    // ---- per-wave invariants: B-frags (We^T), att, xr ----
    bf16x8 bf[8];
    float  atv[8], xrv[8];
    #pragma unroll
    for (int dt = 0; dt < 8; ++dt) {
        bf[dt]  = *(const bf16x8*)&WeT_s[dt * 16 + col][g * 8];
        atv[dt] = att_s[dt * 16 + col];
        xrv[dt] = xr_s[dt * 16 + col];
    }

    // ---- score phase: wave owns j in [wave*128, wave*128+128) ----
    for (int s = 0; s < 8; ++s) {
        const int jt = wave * 128 + s * 16;
        // A-frag: e[b,i, jt+col, g*8 .. g*8+7], f32 -> bf16
        const float* ap = eb + (size_t)(jt + col) * DE + g * 8;
        const f32x4 a0 = *(const f32x4*)ap;
        const f32x4 a1 = *(const f32x4*)(ap + 4);
        bf16x8 af;
        af[0] = f2bf(a0[0]); af[1] = f2bf(a0[1]);
        af[2] = f2bf(a0[2]); af[3] = f2bf(a0[3]);
        af[4] = f2bf(a1[0]); af[5] = f2bf(a1[1]);
        af[6] = f2bf(a1[2]); af[7] = f2bf(a1[3]);

        f32x4 z = {0.f, 0.f, 0.f, 0.f};
        f32x4 c[8];
        #pragma unroll
        for (int dt = 0; dt < 8; ++dt)
            c[dt] = __builtin_amdgcn_mfma_f32_16x16x32_bf16(af, bf[dt], z, 0, 0, 0);

        // epilogue: pre = C + xr + xl ; leaky ; att-dot (partial over this lane's d)
        float part[4] = {0.f, 0.f, 0.f, 0.f};
        #pragma unroll
        for (int dt = 0; dt < 8; ++dt) {
            const int d = dt * 16 + col;
            const float* xp = xlb + (size_t)(jt + g * 4) * DOUT + d;
            #pragma unroll
            for (int r = 0; r < 4; ++r) {
                float p = c[dt][r] + xrv[dt] + xp[(size_t)r * DOUT];
                p = p > 0.f ? p : NEG * p;
                part[r] = fmaf(atv[dt], p, part[r]);
            }
        }
        #pragma unroll
        for (int r = 0; r < 4; ++r) {
            part[r] += __shfl_xor(part[r], 1, 64);
            part[r] += __shfl_xor(part[r], 2, 64);
            part[r] += __shfl_xor(part[r], 4, 64);
            part[r] += __shfl_xor(part[r], 8, 64);
        }
        if (col == 0) {
            #pragma unroll
            for (int r = 0; r < 4; ++r) {
                const int j = jt + g * 4 + r;
                const bool conn = (j == i) ||
                    (byteMode ? (adjB[j] != 0) : (adjW[j] != 0));
                sc_s[j] = conn ? part[r] : -1e30f;
            }
        }
    }
    __syncthreads();

    // ---- softmax over 512 scores ----
    float m = fmaxf(sc_s[t], sc_s[t + 256]);
    #pragma unroll
    for (int off = 32; off; off >>= 1) m = fmaxf(m, __shfl_xor(m, off, 64));
    if (lane == 0) red_s[wave] = m;
    __syncthreads();
    m = fmaxf(fmaxf(red_s[0], red_s[1]), fmaxf(red_s[2], red_s[3]));

    const float e0 = __expf(sc_s[t] - m);
    const float e1 = __expf(sc_s[t + 256] - m);
    sc_s[t] = e0; sc_s[t + 256] = e1;
    float ssum = e0 + e1;
    #pragma unroll
    for (int off = 32; off; off >>= 1) ssum += __shfl_xor(ssum, off, 64);
    if (lane == 0) red_s[4 + wave] = ssum;
    __syncthreads();
    const float inv = 1.f / (red_s[4] + red_s[5] + red_s[6] + red_s[7]);

    // ---- aggregation: out[d] = (sum_j w_j * xl[j,d]) * inv + bias, mask, silu
    const int d = t & (DOUT - 1), hv = t >> 7;
    float acc = 0.f;
    const float* xlh  = xlb + (size_t)hv * 256 * DOUT;
    const float* wrow = sc_s + hv * 256;
    for (int j = 0; j < 256; ++j)
        acc = fmaf(wrow[j], xlh[(size_t)j * DOUT + d], acc);
    op_s[hv][d] = acc;
    __syncthreads();

    if (t < DOUT) {
        const bool mv = byteMode ? (((const unsigned char*)maskv)[bi] != 0)
                                 : (((const unsigned*)maskv)[bi] != 0);
        float v = (op_s[0][t] + op_s[1][t]) * inv + bias[t];
        if (!mv) v = 0.f;
        v = v / (1.f + __expf(-v));          // silu
        out[(size_t)bi * DOUT + t] = v;
    }
}

// ---------------------------------------------------------------------------
extern "C" void kernel_launch(void* const* d_in, const int* in_sizes, int n_in,
                              void* d_out, int out_size, void* d_ws, size_t ws_size,
                              hipStream_t stream)
{
    const float* x    = (const float*)d_in[0];
    const void*  adj  = d_in[1];
    const float* e    = (const float*)d_in[2];
    const void*  mask = d_in[3];
    const float* Wl   = (const float*)d_in[4];
    const float* bl   = (const float*)d_in[5];
    const float* Wr   = (const float*)d_in[6];
    const float* br   = (const float*)d_in[7];
    const float* We   = (const float*)d_in[8];
    const float* att  = (const float*)d_in[9];
    const float* bias = (const float*)d_in[10];
    float*       out  = (float*)d_out;

    float* xl = (float*)d_ws;                              // [B*N, 128]
    float* xr = xl + (size_t)BATCH * NNODE * DOUT;         // [B*N, 128]

    xlr_kernel<<<(BATCH * NNODE) / 4, 256, 0, stream>>>(x, Wl, bl, Wr, br, xl, xr);
    gat_main<<<BATCH * NNODE, 256, 0, stream>>>(xl, xr, adj, e, mask, We,
                                                att, bias, out);
}